// Round 10
// baseline (4108573.864 us; speedup 1.0000x reference)
//
#include <hip/hip_runtime.h>
#include <hip/hip_bf16.h>

#define B_ 16
#define T_ 32
#define N_ 256
#define F_ 128
#define H_ 128
#define HL_ 256
#define FB_K 1500   // poll rounds before falling back to MALL copy (~1 ms)

typedef float f32x4 __attribute__((ext_vector_type(4)));
typedef float f32x2 __attribute__((ext_vector_type(2)));
typedef short bf16x8 __attribute__((ext_vector_type(8)));

#define MFMA16(A, Bv, C) __builtin_amdgcn_mfma_f32_16x16x32_bf16((A), (Bv), (C), 0, 0, 0)

__device__ __forceinline__ unsigned short f2bf(float f) {
    unsigned u = __builtin_bit_cast(unsigned, f);
    return (unsigned short)((u + 0x7FFFu + ((u >> 16) & 1u)) >> 16);
}
__device__ __forceinline__ float bf2f(unsigned short s) {
    unsigned u = ((unsigned)s) << 16;
    return __builtin_bit_cast(float, u);
}

__device__ __forceinline__ bf16x8 cvt8(const float* p) {
    f32x4 a = *(const f32x4*)p;
    f32x4 b = *(const f32x4*)(p + 4);
    bf16x8 r;
    r[0] = (short)f2bf(a[0]); r[1] = (short)f2bf(a[1]);
    r[2] = (short)f2bf(a[2]); r[3] = (short)f2bf(a[3]);
    r[4] = (short)f2bf(b[0]); r[5] = (short)f2bf(b[1]);
    r[6] = (short)f2bf(b[2]); r[7] = (short)f2bf(b[3]);
    return r;
}

__device__ __forceinline__ bf16x8 expand_bits(unsigned b) {
    bf16x8 r;
#pragma unroll
    for (int j = 0; j < 8; ++j) r[j] = (short)(((b >> j) & 1u) ? 0x3F80 : 0);
    return r;
}

__device__ __forceinline__ float sigf(float x) { return 1.f / (1.f + __expf(-x)); }
__device__ __forceinline__ float tanhf_(float x) { float e = __expf(2.f * x); return 1.f - 2.f / (e + 1.f); }

// MALL (sc1) path — always correct, any XCD.
__device__ __forceinline__ unsigned long long ld_u64(const unsigned long long* p) {
    return __hip_atomic_load(p, __ATOMIC_RELAXED, __HIP_MEMORY_SCOPE_AGENT);
}
__device__ __forceinline__ void st_u64(unsigned long long* p, unsigned long long v) {
    __hip_atomic_store(p, v, __ATOMIC_RELAXED, __HIP_MEMORY_SCOPE_AGENT);
}
// XCD-L2 (sc0) path — fast when producer+consumer share an XCD.
__device__ __forceinline__ void st_sc0(unsigned long long* p, unsigned long long v) {
    asm volatile("global_store_dwordx2 %0, %1, off sc0" :: "v"(p), "v"(v) : "memory");
}
__device__ __forceinline__ void ld4_sc0(const unsigned long long* p0, const unsigned long long* p1,
                                        const unsigned long long* p2, const unsigned long long* p3,
                                        unsigned long long& v0, unsigned long long& v1,
                                        unsigned long long& v2, unsigned long long& v3) {
    asm volatile(
        "global_load_dwordx2 %0, %4, off sc0\n\t"
        "global_load_dwordx2 %1, %5, off sc0\n\t"
        "global_load_dwordx2 %2, %6, off sc0\n\t"
        "global_load_dwordx2 %3, %7, off sc0\n\t"
        "s_waitcnt vmcnt(0)"
        : "=&v"(v0), "=&v"(v1), "=&v"(v2), "=&v"(v3)
        : "v"(p0), "v"(p1), "v"(p2), "v"(p3)
        : "memory");
}
__device__ __forceinline__ void ld8_sc0(const unsigned long long* p0, const unsigned long long* p1,
                                        const unsigned long long* p2, const unsigned long long* p3,
                                        const unsigned long long* p4, const unsigned long long* p5,
                                        const unsigned long long* p6, const unsigned long long* p7,
                                        unsigned long long& v0, unsigned long long& v1,
                                        unsigned long long& v2, unsigned long long& v3,
                                        unsigned long long& v4, unsigned long long& v5,
                                        unsigned long long& v6, unsigned long long& v7) {
    asm volatile(
        "global_load_dwordx2 %0, %8, off sc0\n\t"
        "global_load_dwordx2 %1, %9, off sc0\n\t"
        "global_load_dwordx2 %2, %10, off sc0\n\t"
        "global_load_dwordx2 %3, %11, off sc0\n\t"
        "global_load_dwordx2 %4, %12, off sc0\n\t"
        "global_load_dwordx2 %5, %13, off sc0\n\t"
        "global_load_dwordx2 %6, %14, off sc0\n\t"
        "global_load_dwordx2 %7, %15, off sc0\n\t"
        "s_waitcnt vmcnt(0)"
        : "=&v"(v0), "=&v"(v1), "=&v"(v2), "=&v"(v3),
          "=&v"(v4), "=&v"(v5), "=&v"(v6), "=&v"(v7)
        : "v"(p0), "v"(p1), "v"(p2), "v"(p3), "v"(p4), "v"(p5), "v"(p6), "v"(p7)
        : "memory");
}

// ---------------- weight prep: W1^T, W2^T in bf16 ----------------
__global__ void k_prep(const float* __restrict__ W1, const float* __restrict__ W2,
                       unsigned short* __restrict__ w1t, unsigned short* __restrict__ w2t) {
    int idx = blockIdx.x * 256 + threadIdx.x;
    int h = idx >> 7, f = idx & 127;
    w1t[idx] = f2bf(W1[f * 128 + h]);
    w2t[idx] = f2bf(W2[f * 128 + h]);
}

// ================= fused GCN + xg + dataflow LSTM =================
// Roles claimed dynamically: XCD0 blocks -> LSTM ranks 0..23 (co-XCD => L2 h-exchange);
// everyone else -> GCN work 0..511 (claim order ~ dispatch order => t-ordered).
// If XCC_ID misbehaves, leftover blocks take LSTM ranks and the bounded-spin
// fallback reroutes h polls to the sc1 MALL copy (round-9 semantics).
__global__ __launch_bounds__(512, 1) void k_fused(
    const int* __restrict__ adj, const float* __restrict__ x,
    const unsigned short* __restrict__ w1t, const unsigned short* __restrict__ w2t,
    const float* __restrict__ b1, const float* __restrict__ b2,
    const float* __restrict__ Wih0, const float* __restrict__ bih0,
    const float* __restrict__ bhh0, const float* __restrict__ Whh0,
    const float* __restrict__ Wih1, const float* __restrict__ Whh1,
    const float* __restrict__ bih1, const float* __restrict__ bhh1,
    const float* __restrict__ Wfc, const float* __restrict__ bfc,
    unsigned long long* xgw,
    unsigned long long* h0M, unsigned long long* h1M,
    unsigned long long* h0L, unsigned long long* h1L,
    int* cnt, float* __restrict__ out) {
    __shared__ __align__(16) char arena[118784];
    __shared__ int s_role;
    const int tid = threadIdx.x;
    const int lane = tid & 63;

    if (tid == 0) {
        // HW_REG_XCC_ID (id 20), offset 0, size 32 -> imm 63508 [m09]
        unsigned xcc = __builtin_amdgcn_s_getreg(63508) & 15u;
        int r = (xcc == 0u) ? atomicAdd(cnt, 1) : (1 << 30);
        if (r >= 24) {
            int g = atomicAdd(cnt + 1, 1);
            if (g < 512) r = 24 + g;
            else r = atomicAdd(cnt, 1);   // GCN exhausted: claim leftover LSTM rank
        }
        s_role = r;
    }
    __syncthreads();
    const int role = s_role;

    if (role >= 24) {
        // ===================== GCN role =====================
        const int k = role - 24;
        const int t = k >> 4, b = k & 15;
        const int bt_in = b * 32 + t;
        unsigned short* s_ft = (unsigned short*)arena;
        unsigned short* s_w  = (unsigned short*)(arena + 69632);
        unsigned char*  s_bm = (unsigned char*)(arena + 104448);
        float* s_dinv = (float*)(arena + 112640);
        float* s_b1   = (float*)(arena + 113664);
        float* s_b2   = (float*)(arena + 114176);
        float* s_pool = (float*)(arena + 114688);
        const int* adjb = adj + (size_t)bt_in * (N_ * N_);

        for (int it = 0; it < 16; ++it) {
            int row = it * 16 + (tid >> 5);
            int c = tid & 31, m0 = c * 8;
            const int* p = adjb + row * N_ + m0;
            int4 q0 = *(const int4*)p;
            int4 q1 = *(const int4*)(p + 4);
            unsigned by = 0;
            by |= (((q0.x != 0) | (m0 + 0 == row)) ? 1u : 0u);
            by |= (((q0.y != 0) | (m0 + 1 == row)) ? 2u : 0u);
            by |= (((q0.z != 0) | (m0 + 2 == row)) ? 4u : 0u);
            by |= (((q0.w != 0) | (m0 + 3 == row)) ? 8u : 0u);
            by |= (((q1.x != 0) | (m0 + 4 == row)) ? 16u : 0u);
            by |= (((q1.y != 0) | (m0 + 5 == row)) ? 32u : 0u);
            by |= (((q1.z != 0) | (m0 + 6 == row)) ? 64u : 0u);
            by |= (((q1.w != 0) | (m0 + 7 == row)) ? 128u : 0u);
            s_bm[row * 32 + c] = (unsigned char)by;
            int pc = __popc(by);
            pc += __shfl_xor(pc, 1); pc += __shfl_xor(pc, 2); pc += __shfl_xor(pc, 4);
            pc += __shfl_xor(pc, 8); pc += __shfl_xor(pc, 16);
            if (c == 0) s_dinv[row] = rsqrtf((float)pc);
        }
        for (int it = 0; it < 4; ++it) {
            int g = it * 512 + tid;
            *(int4*)(&s_w[(g >> 4) * 136 + (g & 15) * 8]) = *(const int4*)(w1t + g * 8);
        }
        if (tid < 32) *(float4*)(&s_b1[tid * 4]) = *(const float4*)(b1 + tid * 4);
        else if (tid < 64) *(float4*)(&s_b2[(tid - 32) * 4]) = *(const float4*)(b2 + (tid - 32) * 4);
        __syncthreads();

        const int w = tid >> 6, li = lane & 15, lg = lane >> 4;
        const float* xb = x + (size_t)bt_in * (N_ * F_);
        f32x4 acc[2][8];

        // phase 1: XWT' = dinv .* (x@W1)^T
#pragma unroll
        for (int a = 0; a < 2; ++a)
#pragma unroll
            for (int c = 0; c < 8; ++c) acc[a][c] = (f32x4){0.f, 0.f, 0.f, 0.f};
#pragma unroll
        for (int ks = 0; ks < 4; ++ks) {
            bf16x8 a0 = cvt8(xb + (size_t)(32 * w + li) * F_ + lg * 8 + ks * 32);
            bf16x8 a1 = cvt8(xb + (size_t)(32 * w + 16 + li) * F_ + lg * 8 + ks * 32);
#pragma unroll
            for (int ct = 0; ct < 8; ++ct) {
                bf16x8 bv = *(const bf16x8*)(&s_w[(16 * ct + li) * 136 + lg * 8 + ks * 32]);
                acc[0][ct] = MFMA16(a0, bv, acc[0][ct]);
                acc[1][ct] = MFMA16(a1, bv, acc[1][ct]);
            }
        }
        __syncthreads();
#pragma unroll
        for (int rt = 0; rt < 2; ++rt) {
            int m0 = 32 * w + 16 * rt + 4 * lg;
            f32x4 dv = *(const f32x4*)(&s_dinv[m0]);
#pragma unroll
            for (int ct = 0; ct < 8; ++ct) {
                int h = 16 * ct + li;
                f32x4 v = acc[rt][ct];
                unsigned p0 = (unsigned)f2bf(v[0] * dv[0]) | ((unsigned)f2bf(v[1] * dv[1]) << 16);
                unsigned p1 = (unsigned)f2bf(v[2] * dv[2]) | ((unsigned)f2bf(v[3] * dv[3]) << 16);
                uint2 pk; pk.x = p0; pk.y = p1;
                *(uint2*)(&s_ft[h * 264 + m0]) = pk;
            }
        }
        for (int it = 0; it < 4; ++it) {
            int g = it * 512 + tid;
            *(int4*)(&s_w[(g >> 4) * 136 + (g & 15) * 8]) = *(const int4*)(w2t + g * 8);
        }
        __syncthreads();

        // phase 2: h1 = relu(norm@XWT + b1)
#pragma unroll
        for (int a = 0; a < 2; ++a)
#pragma unroll
            for (int c = 0; c < 8; ++c) acc[a][c] = (f32x4){0.f, 0.f, 0.f, 0.f};
#pragma unroll
        for (int ks = 0; ks < 8; ++ks) {
            bf16x8 a0 = expand_bits(s_bm[(32 * w + li) * 32 + 4 * ks + lg]);
            bf16x8 a1 = expand_bits(s_bm[(32 * w + 16 + li) * 32 + 4 * ks + lg]);
#pragma unroll
            for (int ct = 0; ct < 8; ++ct) {
                bf16x8 bv = *(const bf16x8*)(&s_ft[(16 * ct + li) * 264 + lg * 8 + ks * 32]);
                acc[0][ct] = MFMA16(a0, bv, acc[0][ct]);
                acc[1][ct] = MFMA16(a1, bv, acc[1][ct]);
            }
        }
        __syncthreads();
#pragma unroll
        for (int rt = 0; rt < 2; ++rt) {
            int i0 = 32 * w + 16 * rt + 4 * lg;
            f32x4 dv = *(const f32x4*)(&s_dinv[i0]);
#pragma unroll
            for (int ct = 0; ct < 8; ++ct) {
                int h = 16 * ct + li;
                float bb = s_b1[h];
#pragma unroll
                for (int r = 0; r < 4; ++r)
                    s_ft[(i0 + r) * 136 + h] = f2bf(fmaxf(acc[rt][ct][r] * dv[r] + bb, 0.f));
            }
        }
        __syncthreads();

        // phase 3: FT2' = dinv .* (h1@W2)^T
#pragma unroll
        for (int a = 0; a < 2; ++a)
#pragma unroll
            for (int c = 0; c < 8; ++c) acc[a][c] = (f32x4){0.f, 0.f, 0.f, 0.f};
#pragma unroll
        for (int ks = 0; ks < 4; ++ks) {
            bf16x8 a0 = *(const bf16x8*)(&s_ft[(32 * w + li) * 136 + lg * 8 + ks * 32]);
            bf16x8 a1 = *(const bf16x8*)(&s_ft[(32 * w + 16 + li) * 136 + lg * 8 + ks * 32]);
#pragma unroll
            for (int ct = 0; ct < 8; ++ct) {
                bf16x8 bv = *(const bf16x8*)(&s_w[(16 * ct + li) * 136 + lg * 8 + ks * 32]);
                acc[0][ct] = MFMA16(a0, bv, acc[0][ct]);
                acc[1][ct] = MFMA16(a1, bv, acc[1][ct]);
            }
        }
        __syncthreads();
#pragma unroll
        for (int rt = 0; rt < 2; ++rt) {
            int m0 = 32 * w + 16 * rt + 4 * lg;
            f32x4 dv = *(const f32x4*)(&s_dinv[m0]);
#pragma unroll
            for (int ct = 0; ct < 8; ++ct) {
                int h = 16 * ct + li;
                f32x4 v = acc[rt][ct];
                unsigned p0 = (unsigned)f2bf(v[0] * dv[0]) | ((unsigned)f2bf(v[1] * dv[1]) << 16);
                unsigned p1 = (unsigned)f2bf(v[2] * dv[2]) | ((unsigned)f2bf(v[3] * dv[3]) << 16);
                uint2 pk; pk.x = p0; pk.y = p1;
                *(uint2*)(&s_ft[h * 264 + m0]) = pk;
            }
        }
        __syncthreads();

        // phase 4: h2 + mean-pool
#pragma unroll
        for (int a = 0; a < 2; ++a)
#pragma unroll
            for (int c = 0; c < 8; ++c) acc[a][c] = (f32x4){0.f, 0.f, 0.f, 0.f};
#pragma unroll
        for (int ks = 0; ks < 8; ++ks) {
            bf16x8 a0 = expand_bits(s_bm[(32 * w + li) * 32 + 4 * ks + lg]);
            bf16x8 a1 = expand_bits(s_bm[(32 * w + 16 + li) * 32 + 4 * ks + lg]);
#pragma unroll
            for (int ct = 0; ct < 8; ++ct) {
                bf16x8 bv = *(const bf16x8*)(&s_ft[(16 * ct + li) * 264 + lg * 8 + ks * 32]);
                acc[0][ct] = MFMA16(a0, bv, acc[0][ct]);
                acc[1][ct] = MFMA16(a1, bv, acc[1][ct]);
            }
        }
        int i0a = 32 * w + 4 * lg;
        f32x4 dv0 = *(const f32x4*)(&s_dinv[i0a]);
        f32x4 dv1 = *(const f32x4*)(&s_dinv[i0a + 16]);
#pragma unroll
        for (int ct = 0; ct < 8; ++ct) {
            int h = 16 * ct + li;
            float bb = s_b2[h];
            float s = 0.f;
#pragma unroll
            for (int r = 0; r < 4; ++r) {
                s += fmaxf(acc[0][ct][r] * dv0[r] + bb, 0.f);
                s += fmaxf(acc[1][ct][r] * dv1[r] + bb, 0.f);
            }
            s += __shfl_xor(s, 16);
            s += __shfl_xor(s, 32);
            if (lg == 0) s_pool[w * 128 + h] = s;
        }
        __syncthreads();
        float* s_emb = s_dinv;
        if (tid < 128) {
            float e = 0.f;
#pragma unroll
            for (int ww = 0; ww < 8; ++ww) e += s_pool[ww * 128 + tid];
            s_emb[tid] = e * (1.f / 256.f);
        }
        __syncthreads();

        // xg row publish (sc1 MALL, epoch=1)
        const f32x4* ev = (const f32x4*)s_emb;
#pragma unroll
        for (int cc = 0; cc < 2; ++cc) {
            int col = cc * 512 + tid;
            float a = bih0[col] + bhh0[col];
            const f32x4* wr = (const f32x4*)(Wih0 + (size_t)col * 128);
            float a0 = 0.f, a1 = 0.f, a2 = 0.f, a3 = 0.f;
            for (int k4 = 0; k4 < 32; k4 += 4) {
                f32x4 w0 = wr[k4], w1 = wr[k4 + 1], w2 = wr[k4 + 2], w3 = wr[k4 + 3];
                f32x4 e0 = ev[k4], e1 = ev[k4 + 1], e2 = ev[k4 + 2], e3 = ev[k4 + 3];
                a0 += w0[0]*e0[0] + w0[1]*e0[1] + w0[2]*e0[2] + w0[3]*e0[3];
                a1 += w1[0]*e1[0] + w1[1]*e1[1] + w1[2]*e1[2] + w1[3]*e1[3];
                a2 += w2[0]*e2[0] + w2[1]*e2[1] + w2[2]*e2[2] + w2[3]*e2[3];
                a3 += w3[0]*e3[0] + w3[1]*e3[1] + w3[2]*e3[2] + w3[3]*e3[3];
            }
            float v = a + ((a0 + a1) + (a2 + a3));
            unsigned long long pk = (unsigned long long)__builtin_bit_cast(unsigned, v)
                                  | (1ull << 32);
            st_u64(xgw + (size_t)k * 1024 + col, pk);
        }
    } else if (role < 8) {
        // ===================== LSTM layer 0 =====================
        unsigned short* s_w = (unsigned short*)arena;
        unsigned short* s_h = (unsigned short*)(arena + 66048);
        float* s_gate = (float*)(arena + 74304);
        const int j0 = role * 32;

#pragma unroll
        for (int it = 0; it < 16; ++it) {
            int e4 = tid + it * 512;
            int rl = e4 >> 6, k0 = (e4 & 63) * 4;
            int rg = (rl >> 5) * 256 + j0 + (rl & 31);
            float4 v = *(const float4*)(Whh0 + (size_t)rg * 256 + k0);
            uint2 pk;
            pk.x = (unsigned)f2bf(v.x) | ((unsigned)f2bf(v.y) << 16);
            pk.y = (unsigned)f2bf(v.z) | ((unsigned)f2bf(v.w) << 16);
            *(uint2*)(s_w + rl * 258 + k0) = pk;
        }
        __syncthreads();

        const int w = tid >> 6, li = lane & 15, lg = lane >> 4;
        const int cb = tid >> 5, cj = tid & 31;
        float c_reg = 0.f;
        bool fb = false;

        for (int t = 0; t < 32; ++t) {
            // xg wait (sc1; steady-state instant)
            const unsigned long long* xsrc = xgw + (size_t)(t * 16 + cb) * 1024 + j0 + cj;
            unsigned long long xv[4];
            for (;;) {
#pragma unroll
                for (int g = 0; g < 4; ++g) xv[g] = ld_u64(xsrc + g * 256);
                bool ok = true;
#pragma unroll
                for (int g = 0; g < 4; ++g) ok &= ((unsigned)(xv[g] >> 32) == 1u);
                if (ok) break;
                __builtin_amdgcn_s_sleep(1);
            }
            if (t > 0) {
                // h wait: sc0 L2 fast path with bounded-spin MALL fallback
                const size_t off = (size_t)(t - 1) * 2048 + tid;
                const unsigned long long* pL = h0L + off;
                const unsigned long long* pM = h0M + off;
                unsigned long long v0, v1, v2, v3;
                const unsigned e = (unsigned)t;
                int spin = 0;
                for (;;) {
                    if (!fb) {
                        ld4_sc0(pL, pL + 512, pL + 1024, pL + 1536, v0, v1, v2, v3);
                    } else {
                        v0 = ld_u64(pM); v1 = ld_u64(pM + 512);
                        v2 = ld_u64(pM + 1024); v3 = ld_u64(pM + 1536);
                    }
                    bool ok = ((unsigned)(v0 >> 32) == e) & ((unsigned)(v1 >> 32) == e)
                            & ((unsigned)(v2 >> 32) == e) & ((unsigned)(v3 >> 32) == e);
                    if (ok) break;
                    if (!fb && ++spin > FB_K) fb = true;
                    __builtin_amdgcn_s_sleep(1);
                }
                unsigned long long vv[4] = {v0, v1, v2, v3};
#pragma unroll
                for (int q = 0; q < 4; ++q) {
                    int wd = tid + q * 512;
                    int b = wd >> 7, jp = wd & 127;
                    *(unsigned*)(s_h + b * 258 + jp * 2) = (unsigned)vv[q];
                }
            }
            __syncthreads();
            if (t > 0) {
                f32x4 acc = (f32x4){0.f, 0.f, 0.f, 0.f};
#pragma unroll
                for (int ks = 0; ks < 8; ++ks) {
                    bf16x8 af = *(const bf16x8*)(s_h + li * 258 + lg * 8 + ks * 32);
                    bf16x8 bf = *(const bf16x8*)(s_w + (16 * w + li) * 258 + lg * 8 + ks * 32);
                    acc = MFMA16(af, bf, acc);
                }
                int base = (16 * w + li) * 18 + 4 * lg;
                *(f32x2*)(s_gate + base) = (f32x2){acc[0], acc[1]};
                *(f32x2*)(s_gate + base + 2) = (f32x2){acc[2], acc[3]};
            }
            __syncthreads();
            {
                float gi = __builtin_bit_cast(float, (unsigned)xv[0]);
                float gf = __builtin_bit_cast(float, (unsigned)xv[1]);
                float gg = __builtin_bit_cast(float, (unsigned)xv[2]);
                float go = __builtin_bit_cast(float, (unsigned)xv[3]);
                if (t > 0) {
                    gi += s_gate[(0 * 32 + cj) * 18 + cb];
                    gf += s_gate[(1 * 32 + cj) * 18 + cb];
                    gg += s_gate[(2 * 32 + cj) * 18 + cb];
                    go += s_gate[(3 * 32 + cj) * 18 + cb];
                }
                c_reg = sigf(gf) * c_reg + sigf(gi) * tanhf_(gg);
                float h = sigf(go) * tanhf_(c_reg);
                unsigned hu = f2bf(h);
                unsigned other = __shfl_xor(hu, 1);
                if ((cj & 1) == 0) {
                    unsigned long long v = (unsigned long long)(hu | (other << 16))
                                         | ((unsigned long long)(t + 1) << 32);
                    size_t off = (size_t)t * 2048 + cb * 128 + ((j0 + cj) >> 1);
                    st_sc0(h0L + off, v);   // fast local-XCD L2 copy
                    st_u64(h0M + off, v);   // always-correct MALL copy
                }
            }
        }
    } else {
        // ===================== LSTM layer 1 =====================
        unsigned short* s_w = (unsigned short*)arena;
        unsigned short* s_h = (unsigned short*)(arena + 65792);
        float* s_gate = (float*)(arena + 82240);
        const int bi = role - 8;
        const int j0 = bi * 16;

#pragma unroll
        for (int it = 0; it < 16; ++it) {
            int e4 = tid + it * 512;
            int rl = e4 >> 7, k0 = (e4 & 127) * 4;
            int rg = (rl >> 4) * 256 + j0 + (rl & 15);
            const float* src = (k0 < 256) ? (Wih1 + (size_t)rg * 256 + k0)
                                          : (Whh1 + (size_t)rg * 256 + (k0 - 256));
            float4 v = *(const float4*)src;
            uint2 pk;
            pk.x = (unsigned)f2bf(v.x) | ((unsigned)f2bf(v.y) << 16);
            pk.y = (unsigned)f2bf(v.z) | ((unsigned)f2bf(v.w) << 16);
            *(uint2*)(s_w + rl * 514 + k0) = pk;
        }

        const int w = tid >> 6, li = lane & 15, lg = lane >> 4;
        const int ct = w & 3, kh = w >> 2;
        const int cb = tid >> 4, cj = tid & 15;
        float bias[4];
        if (tid < 256) {
#pragma unroll
            for (int g = 0; g < 4; ++g) {
                int r = g * 256 + j0 + cj;
                bias[g] = bih1[r] + bhh1[r];
            }
        }
        __syncthreads();
        float c_reg = 0.f;
        bool fb = false;

        for (int t = 0; t < 32; ++t) {
            const size_t o0 = (size_t)t * 2048 + tid;
            const size_t o1 = (size_t)(t - 1) * 2048 + tid;
            unsigned long long v0, v1, v2, v3, v4, v5, v6, v7;
            const unsigned e0 = (unsigned)(t + 1), e1 = (unsigned)t;
            int spin = 0;
            if (t > 0) {
                const unsigned long long* aL = h0L + o0;
                const unsigned long long* bL = h1L + o1;
                const unsigned long long* aM = h0M + o0;
                const unsigned long long* bM = h1M + o1;
                for (;;) {
                    if (!fb) {
                        ld8_sc0(aL, aL + 512, aL + 1024, aL + 1536,
                                bL, bL + 512, bL + 1024, bL + 1536,
                                v0, v1, v2, v3, v4, v5, v6, v7);
                    } else {
                        v0 = ld_u64(aM); v1 = ld_u64(aM + 512);
                        v2 = ld_u64(aM + 1024); v3 = ld_u64(aM + 1536);
                        v4 = ld_u64(bM); v5 = ld_u64(bM + 512);
                        v6 = ld_u64(bM + 1024); v7 = ld_u64(bM + 1536);
                    }
                    bool ok = ((unsigned)(v0 >> 32) == e0) & ((unsigned)(v1 >> 32) == e0)
                            & ((unsigned)(v2 >> 32) == e0) & ((unsigned)(v3 >> 32) == e0)
                            & ((unsigned)(v4 >> 32) == e1) & ((unsigned)(v5 >> 32) == e1)
                            & ((unsigned)(v6 >> 32) == e1) & ((unsigned)(v7 >> 32) == e1);
                    if (ok) break;
                    if (!fb && ++spin > FB_K) fb = true;
                    __builtin_amdgcn_s_sleep(1);
                }
            } else {
                const unsigned long long* aL = h0L + o0;
                const unsigned long long* aM = h0M + o0;
                for (;;) {
                    if (!fb) {
                        ld4_sc0(aL, aL + 512, aL + 1024, aL + 1536, v0, v1, v2, v3);
                    } else {
                        v0 = ld_u64(aM); v1 = ld_u64(aM + 512);
                        v2 = ld_u64(aM + 1024); v3 = ld_u64(aM + 1536);
                    }
                    bool ok = ((unsigned)(v0 >> 32) == e0) & ((unsigned)(v1 >> 32) == e0)
                            & ((unsigned)(v2 >> 32) == e0) & ((unsigned)(v3 >> 32) == e0);
                    if (ok) break;
                    if (!fb && ++spin > FB_K) fb = true;
                    __builtin_amdgcn_s_sleep(1);
                }
                v4 = v5 = v6 = v7 = 0ull;
            }
            unsigned long long vv[8] = {v0, v1, v2, v3, v4, v5, v6, v7};
#pragma unroll
            for (int q = 0; q < 4; ++q) {
                int wd = tid + q * 512;
                int b = wd >> 7, jp = wd & 127;
                *(unsigned*)(s_h + b * 514 + jp * 2) = (unsigned)vv[q];
                *(unsigned*)(s_h + b * 514 + 256 + jp * 2) = (unsigned)vv[4 + q];
            }
            __syncthreads();
            {
                f32x4 acc = (f32x4){0.f, 0.f, 0.f, 0.f};
#pragma unroll
                for (int ks = 0; ks < 8; ++ks) {
                    int ko = (kh * 8 + ks) * 32;
                    bf16x8 af = *(const bf16x8*)(s_h + li * 514 + lg * 8 + ko);
                    bf16x8 bf = *(const bf16x8*)(s_w + (16 * ct + li) * 514 + lg * 8 + ko);
                    acc = MFMA16(af, bf, acc);
                }
                int base = kh * 1152 + (16 * ct + li) * 18 + 4 * lg;
                *(f32x2*)(s_gate + base) = (f32x2){acc[0], acc[1]};
                *(f32x2*)(s_gate + base + 2) = (f32x2){acc[2], acc[3]};
            }
            __syncthreads();
            if (tid < 256) {
                float gt[4];
#pragma unroll
                for (int g = 0; g < 4; ++g) {
                    int base = (g * 16 + cj) * 18 + cb;
                    gt[g] = s_gate[base] + s_gate[1152 + base] + bias[g];
                }
                c_reg = sigf(gt[1]) * c_reg + sigf(gt[0]) * tanhf_(gt[2]);
                float h = sigf(gt[3]) * tanhf_(c_reg);
                unsigned hu = f2bf(h);
                unsigned other = __shfl_xor(hu, 1);
                if ((cj & 1) == 0) {
                    unsigned long long v2w = (unsigned long long)(hu | (other << 16))
                                           | ((unsigned long long)(t + 1) << 32);
                    size_t off = (size_t)t * 2048 + cb * 128 + ((j0 + cj) >> 1);
                    st_sc0(h1L + off, v2w);
                    st_u64(h1M + off, v2w);
                }
            }
        }

        if (bi == 0) {
            // FC + sigmoid on h1[31] via the always-correct MALL copy
            float* s_red = s_gate;
            if (tid < 256) {
                int b = tid >> 4, kc = tid & 15;
                const unsigned long long* hw = h1M + (size_t)31 * 2048 + b * 128 + kc * 8;
                unsigned long long v[8];
                for (;;) {
#pragma unroll
                    for (int q = 0; q < 8; ++q) v[q] = ld_u64(hw + q);
                    bool ok = true;
#pragma unroll
                    for (int q = 0; q < 8; ++q) ok &= ((unsigned)(v[q] >> 32) == 32u);
                    if (ok) break;
                    __builtin_amdgcn_s_sleep(1);
                }
                float s = 0.f;
#pragma unroll
                for (int q = 0; q < 8; ++q) {
                    unsigned u = (unsigned)v[q];
                    s += Wfc[kc * 16 + 2 * q] * bf2f((unsigned short)(u & 0xffff));
                    s += Wfc[kc * 16 + 2 * q + 1] * bf2f((unsigned short)(u >> 16));
                }
                s_red[tid] = s;
            }
            __syncthreads();
            if (tid < 16) {
                float s = bfc[0];
#pragma unroll
                for (int q = 0; q < 16; ++q) s += s_red[tid * 16 + q];
                out[tid] = sigf(s);
            }
        }
    }
}

extern "C" void kernel_launch(void* const* d_in, const int* in_sizes, int n_in,
                              void* d_out, int out_size, void* d_ws, size_t ws_size,
                              hipStream_t stream) {
    const int*   adj  = (const int*)  d_in[0];
    const float* x    = (const float*)d_in[1];
    const float* W1   = (const float*)d_in[2];
    const float* b1   = (const float*)d_in[3];
    const float* W2   = (const float*)d_in[4];
    const float* b2   = (const float*)d_in[5];
    const float* Wih0 = (const float*)d_in[6];
    const float* Whh0 = (const float*)d_in[7];
    const float* bih0 = (const float*)d_in[8];
    const float* bhh0 = (const float*)d_in[9];
    const float* Wih1 = (const float*)d_in[10];
    const float* Whh1 = (const float*)d_in[11];
    const float* bih1 = (const float*)d_in[12];
    const float* bhh1 = (const float*)d_in[13];
    const float* Wfc  = (const float*)d_in[14];
    const float* bfc  = (const float*)d_in[15];
    float* out = (float*)d_out;

    if (ws_size < 6425600) return;   // ~6.2 MB scratch

    char* ws = (char*)d_ws;
    unsigned long long* xgw = (unsigned long long*)(ws);             // 4,194,304 B
    unsigned long long* h0M = (unsigned long long*)(ws + 4194304);   //   524,288 B
    unsigned long long* h1M = (unsigned long long*)(ws + 4718592);   //   524,288 B
    unsigned long long* h0L = (unsigned long long*)(ws + 5242880);   //   524,288 B
    unsigned long long* h1L = (unsigned long long*)(ws + 5767168);   //   524,288 B
    int*                cnt = (int*)(ws + 6291456);                  //         8 B
    unsigned short*     w1t = (unsigned short*)(ws + 6292480);       //    32,768 B
    unsigned short*     w2t = (unsigned short*)(ws + 6325248);       //    32,768 B

    hipMemsetAsync(ws, 0, 6292480, stream);   // zero xg + all h epochs + counters
    k_prep<<<64, 256, 0, stream>>>(W1, W2, w1t, w2t);
    k_fused<<<536, 512, 0, stream>>>(adj, x, w1t, w2t, b1, b2,
                                     Wih0, bih0, bhh0, Whh0, Wih1, Whh1,
                                     bih1, bhh1, Wfc, bfc,
                                     xgw, h0M, h1M, h0L, h1L, cnt, out);
}

// Round 11
// 246.405 us; speedup vs baseline: 16674.0843x; 16674.0843x over previous
//
#include <hip/hip_runtime.h>
#include <hip/hip_bf16.h>

#define B_ 16
#define T_ 32
#define N_ 256
#define F_ 128
#define H_ 128
#define HL_ 256

typedef float f32x4 __attribute__((ext_vector_type(4)));
typedef float f32x2 __attribute__((ext_vector_type(2)));
typedef short bf16x8 __attribute__((ext_vector_type(8)));

#define MFMA16(A, Bv, C) __builtin_amdgcn_mfma_f32_16x16x32_bf16((A), (Bv), (C), 0, 0, 0)

__device__ __forceinline__ unsigned short f2bf(float f) {
    unsigned u = __builtin_bit_cast(unsigned, f);
    return (unsigned short)((u + 0x7FFFu + ((u >> 16) & 1u)) >> 16);
}
__device__ __forceinline__ float bf2f(unsigned short s) {
    unsigned u = ((unsigned)s) << 16;
    return __builtin_bit_cast(float, u);
}

__device__ __forceinline__ bf16x8 cvt8(const float* p) {
    f32x4 a = *(const f32x4*)p;
    f32x4 b = *(const f32x4*)(p + 4);
    bf16x8 r;
    r[0] = (short)f2bf(a[0]); r[1] = (short)f2bf(a[1]);
    r[2] = (short)f2bf(a[2]); r[3] = (short)f2bf(a[3]);
    r[4] = (short)f2bf(b[0]); r[5] = (short)f2bf(b[1]);
    r[6] = (short)f2bf(b[2]); r[7] = (short)f2bf(b[3]);
    return r;
}

__device__ __forceinline__ bf16x8 expand_bits(unsigned b) {
    bf16x8 r;
#pragma unroll
    for (int j = 0; j < 8; ++j) r[j] = (short)(((b >> j) & 1u) ? 0x3F80 : 0);
    return r;
}

__device__ __forceinline__ float sigf(float x) { return 1.f / (1.f + __expf(-x)); }
__device__ __forceinline__ float tanhf_(float x) { float e = __expf(2.f * x); return 1.f - 2.f / (e + 1.f); }

// epoch-tagged u64 word via MALL (sc1): lo 32 = payload, hi 32 = epoch.
__device__ __forceinline__ unsigned long long ld_u64(const unsigned long long* p) {
    return __hip_atomic_load(p, __ATOMIC_RELAXED, __HIP_MEMORY_SCOPE_AGENT);
}
__device__ __forceinline__ void st_u64(unsigned long long* p, unsigned long long v) {
    __hip_atomic_store(p, v, __ATOMIC_RELAXED, __HIP_MEMORY_SCOPE_AGENT);
}

// ---------------- weight prep: W1^T, W2^T in bf16 ----------------
__global__ void k_prep(const float* __restrict__ W1, const float* __restrict__ W2,
                       unsigned short* __restrict__ w1t, unsigned short* __restrict__ w2t) {
    int idx = blockIdx.x * 256 + threadIdx.x;   // 64 blocks * 256 = 16384
    int h = idx >> 7, f = idx & 127;
    w1t[idx] = f2bf(W1[f * 128 + h]);
    w2t[idx] = f2bf(W2[f * 128 + h]);
}

// ================= fused GCN + xg + dataflow LSTM, one launch =================
// blocks 0..7   : LSTM layer0 (dataflow, polls xgw + h0w)
// blocks 8..23  : LSTM layer1 (polls h0w + h1w); block 8 does FC tail
// blocks 24..535: GCN for k=wg-24, t=k>>4, b=k&15 (t-major so xg(t) arrives in order);
//                 computes 2-layer GCN + mean-pool + xg row, publishes xgw epoch-tagged.
// xgw: [32 t][16 b][1024 col] u64 {f32 payload, epoch=1}; h0w/h1w as before.
__global__ __launch_bounds__(512, 1) void k_fused(
    const int* __restrict__ adj, const float* __restrict__ x,
    const unsigned short* __restrict__ w1t, const unsigned short* __restrict__ w2t,
    const float* __restrict__ b1, const float* __restrict__ b2,
    const float* __restrict__ Wih0, const float* __restrict__ bih0,
    const float* __restrict__ bhh0, const float* __restrict__ Whh0,
    const float* __restrict__ Wih1, const float* __restrict__ Whh1,
    const float* __restrict__ bih1, const float* __restrict__ bhh1,
    const float* __restrict__ Wfc, const float* __restrict__ bfc,
    unsigned long long* xgw, unsigned long long* h0w, unsigned long long* h1w,
    float* __restrict__ out) {
    __shared__ __align__(16) char arena[118784];
    const int wg = blockIdx.x, tid = threadIdx.x;
    const int lane = tid & 63;

    if (wg >= 24) {
        // ===================== GCN role =====================
        const int k = wg - 24;
        const int t = k >> 4, b = k & 15;
        const int bt_in = b * 32 + t;                    // input [B][T] index
        unsigned short* s_ft = (unsigned short*)arena;                 // [256][136]/[128][264]
        unsigned short* s_w  = (unsigned short*)(arena + 69632);       // [128][136]
        unsigned char*  s_bm = (unsigned char*)(arena + 104448);       // 8192
        float* s_dinv = (float*)(arena + 112640);                      // 256 f32
        float* s_b1   = (float*)(arena + 113664);                      // 128 f32
        float* s_b2   = (float*)(arena + 114176);                      // 128 f32
        float* s_pool = (float*)(arena + 114688);                      // 8*128 f32
        const int* adjb = adj + (size_t)bt_in * (N_ * N_);

        for (int it = 0; it < 16; ++it) {
            int row = it * 16 + (tid >> 5);
            int c = tid & 31, m0 = c * 8;
            const int* p = adjb + row * N_ + m0;
            int4 q0 = *(const int4*)p;
            int4 q1 = *(const int4*)(p + 4);
            unsigned by = 0;
            by |= (((q0.x != 0) | (m0 + 0 == row)) ? 1u : 0u);
            by |= (((q0.y != 0) | (m0 + 1 == row)) ? 2u : 0u);
            by |= (((q0.z != 0) | (m0 + 2 == row)) ? 4u : 0u);
            by |= (((q0.w != 0) | (m0 + 3 == row)) ? 8u : 0u);
            by |= (((q1.x != 0) | (m0 + 4 == row)) ? 16u : 0u);
            by |= (((q1.y != 0) | (m0 + 5 == row)) ? 32u : 0u);
            by |= (((q1.z != 0) | (m0 + 6 == row)) ? 64u : 0u);
            by |= (((q1.w != 0) | (m0 + 7 == row)) ? 128u : 0u);
            s_bm[row * 32 + c] = (unsigned char)by;
            int pc = __popc(by);
            pc += __shfl_xor(pc, 1); pc += __shfl_xor(pc, 2); pc += __shfl_xor(pc, 4);
            pc += __shfl_xor(pc, 8); pc += __shfl_xor(pc, 16);
            if (c == 0) s_dinv[row] = rsqrtf((float)pc);
        }
        for (int it = 0; it < 4; ++it) {
            int g = it * 512 + tid;
            *(int4*)(&s_w[(g >> 4) * 136 + (g & 15) * 8]) = *(const int4*)(w1t + g * 8);
        }
        if (tid < 32) *(float4*)(&s_b1[tid * 4]) = *(const float4*)(b1 + tid * 4);
        else if (tid < 64) *(float4*)(&s_b2[(tid - 32) * 4]) = *(const float4*)(b2 + (tid - 32) * 4);
        __syncthreads();

        const int w = tid >> 6, li = lane & 15, lg = lane >> 4;
        const float* xb = x + (size_t)bt_in * (N_ * F_);
        f32x4 acc[2][8];

        // phase 1: XWT' = dinv .* (x@W1)^T
#pragma unroll
        for (int a = 0; a < 2; ++a)
#pragma unroll
            for (int c = 0; c < 8; ++c) acc[a][c] = (f32x4){0.f, 0.f, 0.f, 0.f};
#pragma unroll
        for (int ks = 0; ks < 4; ++ks) {
            bf16x8 a0 = cvt8(xb + (size_t)(32 * w + li) * F_ + lg * 8 + ks * 32);
            bf16x8 a1 = cvt8(xb + (size_t)(32 * w + 16 + li) * F_ + lg * 8 + ks * 32);
#pragma unroll
            for (int ct = 0; ct < 8; ++ct) {
                bf16x8 bv = *(const bf16x8*)(&s_w[(16 * ct + li) * 136 + lg * 8 + ks * 32]);
                acc[0][ct] = MFMA16(a0, bv, acc[0][ct]);
                acc[1][ct] = MFMA16(a1, bv, acc[1][ct]);
            }
        }
        __syncthreads();
#pragma unroll
        for (int rt = 0; rt < 2; ++rt) {
            int m0 = 32 * w + 16 * rt + 4 * lg;
            f32x4 dv = *(const f32x4*)(&s_dinv[m0]);
#pragma unroll
            for (int ct = 0; ct < 8; ++ct) {
                int h = 16 * ct + li;
                f32x4 v = acc[rt][ct];
                unsigned p0 = (unsigned)f2bf(v[0] * dv[0]) | ((unsigned)f2bf(v[1] * dv[1]) << 16);
                unsigned p1 = (unsigned)f2bf(v[2] * dv[2]) | ((unsigned)f2bf(v[3] * dv[3]) << 16);
                uint2 pk; pk.x = p0; pk.y = p1;
                *(uint2*)(&s_ft[h * 264 + m0]) = pk;
            }
        }
        for (int it = 0; it < 4; ++it) {
            int g = it * 512 + tid;
            *(int4*)(&s_w[(g >> 4) * 136 + (g & 15) * 8]) = *(const int4*)(w2t + g * 8);
        }
        __syncthreads();

        // phase 2: h1 = relu(norm@XWT + b1)
#pragma unroll
        for (int a = 0; a < 2; ++a)
#pragma unroll
            for (int c = 0; c < 8; ++c) acc[a][c] = (f32x4){0.f, 0.f, 0.f, 0.f};
#pragma unroll
        for (int ks = 0; ks < 8; ++ks) {
            bf16x8 a0 = expand_bits(s_bm[(32 * w + li) * 32 + 4 * ks + lg]);
            bf16x8 a1 = expand_bits(s_bm[(32 * w + 16 + li) * 32 + 4 * ks + lg]);
#pragma unroll
            for (int ct = 0; ct < 8; ++ct) {
                bf16x8 bv = *(const bf16x8*)(&s_ft[(16 * ct + li) * 264 + lg * 8 + ks * 32]);
                acc[0][ct] = MFMA16(a0, bv, acc[0][ct]);
                acc[1][ct] = MFMA16(a1, bv, acc[1][ct]);
            }
        }
        __syncthreads();
#pragma unroll
        for (int rt = 0; rt < 2; ++rt) {
            int i0 = 32 * w + 16 * rt + 4 * lg;
            f32x4 dv = *(const f32x4*)(&s_dinv[i0]);
#pragma unroll
            for (int ct = 0; ct < 8; ++ct) {
                int h = 16 * ct + li;
                float bb = s_b1[h];
#pragma unroll
                for (int r = 0; r < 4; ++r)
                    s_ft[(i0 + r) * 136 + h] = f2bf(fmaxf(acc[rt][ct][r] * dv[r] + bb, 0.f));
            }
        }
        __syncthreads();

        // phase 3: FT2' = dinv .* (h1@W2)^T
#pragma unroll
        for (int a = 0; a < 2; ++a)
#pragma unroll
            for (int c = 0; c < 8; ++c) acc[a][c] = (f32x4){0.f, 0.f, 0.f, 0.f};
#pragma unroll
        for (int ks = 0; ks < 4; ++ks) {
            bf16x8 a0 = *(const bf16x8*)(&s_ft[(32 * w + li) * 136 + lg * 8 + ks * 32]);
            bf16x8 a1 = *(const bf16x8*)(&s_ft[(32 * w + 16 + li) * 136 + lg * 8 + ks * 32]);
#pragma unroll
            for (int ct = 0; ct < 8; ++ct) {
                bf16x8 bv = *(const bf16x8*)(&s_w[(16 * ct + li) * 136 + lg * 8 + ks * 32]);
                acc[0][ct] = MFMA16(a0, bv, acc[0][ct]);
                acc[1][ct] = MFMA16(a1, bv, acc[1][ct]);
            }
        }
        __syncthreads();
#pragma unroll
        for (int rt = 0; rt < 2; ++rt) {
            int m0 = 32 * w + 16 * rt + 4 * lg;
            f32x4 dv = *(const f32x4*)(&s_dinv[m0]);
#pragma unroll
            for (int ct = 0; ct < 8; ++ct) {
                int h = 16 * ct + li;
                f32x4 v = acc[rt][ct];
                unsigned p0 = (unsigned)f2bf(v[0] * dv[0]) | ((unsigned)f2bf(v[1] * dv[1]) << 16);
                unsigned p1 = (unsigned)f2bf(v[2] * dv[2]) | ((unsigned)f2bf(v[3] * dv[3]) << 16);
                uint2 pk; pk.x = p0; pk.y = p1;
                *(uint2*)(&s_ft[h * 264 + m0]) = pk;
            }
        }
        __syncthreads();

        // phase 4: h2 = relu(norm@FT2 + b2); emb = mean_n(h2)
#pragma unroll
        for (int a = 0; a < 2; ++a)
#pragma unroll
            for (int c = 0; c < 8; ++c) acc[a][c] = (f32x4){0.f, 0.f, 0.f, 0.f};
#pragma unroll
        for (int ks = 0; ks < 8; ++ks) {
            bf16x8 a0 = expand_bits(s_bm[(32 * w + li) * 32 + 4 * ks + lg]);
            bf16x8 a1 = expand_bits(s_bm[(32 * w + 16 + li) * 32 + 4 * ks + lg]);
#pragma unroll
            for (int ct = 0; ct < 8; ++ct) {
                bf16x8 bv = *(const bf16x8*)(&s_ft[(16 * ct + li) * 264 + lg * 8 + ks * 32]);
                acc[0][ct] = MFMA16(a0, bv, acc[0][ct]);
                acc[1][ct] = MFMA16(a1, bv, acc[1][ct]);
            }
        }
        int i0a = 32 * w + 4 * lg;
        f32x4 dv0 = *(const f32x4*)(&s_dinv[i0a]);
        f32x4 dv1 = *(const f32x4*)(&s_dinv[i0a + 16]);
#pragma unroll
        for (int ct = 0; ct < 8; ++ct) {
            int h = 16 * ct + li;
            float bb = s_b2[h];
            float s = 0.f;
#pragma unroll
            for (int r = 0; r < 4; ++r) {
                s += fmaxf(acc[0][ct][r] * dv0[r] + bb, 0.f);
                s += fmaxf(acc[1][ct][r] * dv1[r] + bb, 0.f);
            }
            s += __shfl_xor(s, 16);
            s += __shfl_xor(s, 32);
            if (lg == 0) s_pool[w * 128 + h] = s;
        }
        __syncthreads();
        float* s_emb = s_dinv;   // dead after phase 4
        if (tid < 128) {
            float e = 0.f;
#pragma unroll
            for (int ww = 0; ww < 8; ++ww) e += s_pool[ww * 128 + tid];
            s_emb[tid] = e * (1.f / 256.f);
        }
        __syncthreads();

        // xg row: xg[col] = emb . Wih0[col] + bih0[col] + bhh0[col]; publish epoch=1
        const f32x4* ev = (const f32x4*)s_emb;
#pragma unroll
        for (int cc = 0; cc < 2; ++cc) {
            int col = cc * 512 + tid;
            float a = bih0[col] + bhh0[col];
            const f32x4* wr = (const f32x4*)(Wih0 + (size_t)col * 128);
            float a0 = 0.f, a1 = 0.f, a2 = 0.f, a3 = 0.f;
            for (int k4 = 0; k4 < 32; k4 += 4) {
                f32x4 w0 = wr[k4], w1 = wr[k4 + 1], w2 = wr[k4 + 2], w3 = wr[k4 + 3];
                f32x4 e0 = ev[k4], e1 = ev[k4 + 1], e2 = ev[k4 + 2], e3 = ev[k4 + 3];
                a0 += w0[0]*e0[0] + w0[1]*e0[1] + w0[2]*e0[2] + w0[3]*e0[3];
                a1 += w1[0]*e1[0] + w1[1]*e1[1] + w1[2]*e1[2] + w1[3]*e1[3];
                a2 += w2[0]*e2[0] + w2[1]*e2[1] + w2[2]*e2[2] + w2[3]*e2[3];
                a3 += w3[0]*e3[0] + w3[1]*e3[1] + w3[2]*e3[2] + w3[3]*e3[3];
            }
            float v = a + ((a0 + a1) + (a2 + a3));
            unsigned long long pk = (unsigned long long)__builtin_bit_cast(unsigned, v)
                                  | (1ull << 32);
            st_u64(xgw + (size_t)k * 1024 + col, pk);
        }
    } else if (wg < 8) {
        // ===================== LSTM layer 0 =====================
        unsigned short* s_w = (unsigned short*)arena;            // [128][258] bf16
        unsigned short* s_h = (unsigned short*)(arena + 66048);  // [16][258] bf16
        float* s_gate = (float*)(arena + 74304);                 // [128][18] f32
        const int j0 = wg * 32;

#pragma unroll
        for (int it = 0; it < 16; ++it) {
            int e4 = tid + it * 512;
            int rl = e4 >> 6, k0 = (e4 & 63) * 4;
            int rg = (rl >> 5) * 256 + j0 + (rl & 31);
            float4 v = *(const float4*)(Whh0 + (size_t)rg * 256 + k0);
            uint2 pk;
            pk.x = (unsigned)f2bf(v.x) | ((unsigned)f2bf(v.y) << 16);
            pk.y = (unsigned)f2bf(v.z) | ((unsigned)f2bf(v.w) << 16);
            *(uint2*)(s_w + rl * 258 + k0) = pk;
        }
        __syncthreads();

        const int w = tid >> 6, li = lane & 15, lg = lane >> 4;
        const int cb = tid >> 5, cj = tid & 31;
        float c_reg = 0.f;

        for (int t = 0; t < 32; ++t) {
            // batched poll: 4 xg words (+ 4 h words for t>0), one MALL RT per round
            const unsigned long long* xsrc = xgw + (size_t)(t * 16 + cb) * 1024 + j0 + cj;
            unsigned long long xv[4];
            if (t > 0) {
                const unsigned long long* src = h0w + (size_t)(t - 1) * 2048;
                unsigned long long v[4];
                const unsigned e = (unsigned)t;
                for (;;) {
#pragma unroll
                    for (int q = 0; q < 4; ++q) v[q] = ld_u64(src + tid + q * 512);
#pragma unroll
                    for (int g = 0; g < 4; ++g) xv[g] = ld_u64(xsrc + g * 256);
                    bool ok = true;
#pragma unroll
                    for (int q = 0; q < 4; ++q) ok &= ((unsigned)(v[q] >> 32) == e);
#pragma unroll
                    for (int g = 0; g < 4; ++g) ok &= ((unsigned)(xv[g] >> 32) == 1u);
                    if (ok) break;
                    __builtin_amdgcn_s_sleep(1);
                }
#pragma unroll
                for (int q = 0; q < 4; ++q) {
                    int wd = tid + q * 512;
                    int b = wd >> 7, jp = wd & 127;
                    *(unsigned*)(s_h + b * 258 + jp * 2) = (unsigned)v[q];
                }
            } else {
                for (;;) {
#pragma unroll
                    for (int g = 0; g < 4; ++g) xv[g] = ld_u64(xsrc + g * 256);
                    bool ok = true;
#pragma unroll
                    for (int g = 0; g < 4; ++g) ok &= ((unsigned)(xv[g] >> 32) == 1u);
                    if (ok) break;
                    __builtin_amdgcn_s_sleep(1);
                }
            }
            __syncthreads();
            if (t > 0) {
                f32x4 acc = (f32x4){0.f, 0.f, 0.f, 0.f};
#pragma unroll
                for (int ks = 0; ks < 8; ++ks) {
                    bf16x8 af = *(const bf16x8*)(s_h + li * 258 + lg * 8 + ks * 32);
                    bf16x8 bf = *(const bf16x8*)(s_w + (16 * w + li) * 258 + lg * 8 + ks * 32);
                    acc = MFMA16(af, bf, acc);
                }
                int base = (16 * w + li) * 18 + 4 * lg;
                *(f32x2*)(s_gate + base) = (f32x2){acc[0], acc[1]};
                *(f32x2*)(s_gate + base + 2) = (f32x2){acc[2], acc[3]};
            }
            __syncthreads();
            {
                float gi = __builtin_bit_cast(float, (unsigned)xv[0]);
                float gf = __builtin_bit_cast(float, (unsigned)xv[1]);
                float gg = __builtin_bit_cast(float, (unsigned)xv[2]);
                float go = __builtin_bit_cast(float, (unsigned)xv[3]);
                if (t > 0) {
                    gi += s_gate[(0 * 32 + cj) * 18 + cb];
                    gf += s_gate[(1 * 32 + cj) * 18 + cb];
                    gg += s_gate[(2 * 32 + cj) * 18 + cb];
                    go += s_gate[(3 * 32 + cj) * 18 + cb];
                }
                c_reg = sigf(gf) * c_reg + sigf(gi) * tanhf_(gg);
                float h = sigf(go) * tanhf_(c_reg);
                unsigned hu = f2bf(h);
                unsigned other = __shfl_xor(hu, 1);
                if ((cj & 1) == 0) {
                    unsigned long long v = (unsigned long long)(hu | (other << 16))
                                         | ((unsigned long long)(t + 1) << 32);
                    st_u64(h0w + (size_t)t * 2048 + cb * 128 + ((j0 + cj) >> 1), v);
                }
            }
        }
    } else {
        // ===================== LSTM layer 1 =====================
        unsigned short* s_w = (unsigned short*)arena;            // [64][514] bf16
        unsigned short* s_h = (unsigned short*)(arena + 65792);  // [16][514] bf16
        float* s_gate = (float*)(arena + 82240);                 // [2][64][18] f32
        const int bi = wg - 8;
        const int j0 = bi * 16;

#pragma unroll
        for (int it = 0; it < 16; ++it) {
            int e4 = tid + it * 512;
            int rl = e4 >> 7, k0 = (e4 & 127) * 4;
            int rg = (rl >> 4) * 256 + j0 + (rl & 15);
            const float* src = (k0 < 256) ? (Wih1 + (size_t)rg * 256 + k0)
                                          : (Whh1 + (size_t)rg * 256 + (k0 - 256));
            float4 v = *(const float4*)src;
            uint2 pk;
            pk.x = (unsigned)f2bf(v.x) | ((unsigned)f2bf(v.y) << 16);
            pk.y = (unsigned)f2bf(v.z) | ((unsigned)f2bf(v.w) << 16);
            *(uint2*)(s_w + rl * 514 + k0) = pk;
        }

        const int w = tid >> 6, li = lane & 15, lg = lane >> 4;
        const int ct = w & 3, kh = w >> 2;
        const int cb = tid >> 4, cj = tid & 15;
        float bias[4];
        if (tid < 256) {
#pragma unroll
            for (int g = 0; g < 4; ++g) {
                int r = g * 256 + j0 + cj;
                bias[g] = bih1[r] + bhh1[r];
            }
        }
        __syncthreads();
        float c_reg = 0.f;

        for (int t = 0; t < 32; ++t) {
            const unsigned long long* s0 = h0w + (size_t)t * 2048;
            const unsigned long long* s1 = h1w + (size_t)(t - 1) * 2048;
            unsigned long long v[8];
            const unsigned e0 = (unsigned)(t + 1), e1 = (unsigned)t;
            if (t > 0) {
                for (;;) {
#pragma unroll
                    for (int q = 0; q < 4; ++q) v[q] = ld_u64(s0 + tid + q * 512);
#pragma unroll
                    for (int q = 0; q < 4; ++q) v[4 + q] = ld_u64(s1 + tid + q * 512);
                    bool ok = true;
#pragma unroll
                    for (int q = 0; q < 4; ++q) ok &= ((unsigned)(v[q] >> 32) == e0);
#pragma unroll
                    for (int q = 0; q < 4; ++q) ok &= ((unsigned)(v[4 + q] >> 32) == e1);
                    if (ok) break;
                    __builtin_amdgcn_s_sleep(1);
                }
            } else {
                for (;;) {
#pragma unroll
                    for (int q = 0; q < 4; ++q) v[q] = ld_u64(s0 + tid + q * 512);
                    bool ok = true;
#pragma unroll
                    for (int q = 0; q < 4; ++q) ok &= ((unsigned)(v[q] >> 32) == e0);
                    if (ok) break;
                    __builtin_amdgcn_s_sleep(1);
                }
#pragma unroll
                for (int q = 0; q < 4; ++q) v[4 + q] = 0ull;
            }
#pragma unroll
            for (int q = 0; q < 4; ++q) {
                int wd = tid + q * 512;
                int b = wd >> 7, jp = wd & 127;
                *(unsigned*)(s_h + b * 514 + jp * 2) = (unsigned)v[q];
                *(unsigned*)(s_h + b * 514 + 256 + jp * 2) = (unsigned)v[4 + q];
            }
            __syncthreads();
            {
                f32x4 acc = (f32x4){0.f, 0.f, 0.f, 0.f};
#pragma unroll
                for (int ks = 0; ks < 8; ++ks) {
                    int ko = (kh * 8 + ks) * 32;
                    bf16x8 af = *(const bf16x8*)(s_h + li * 514 + lg * 8 + ko);
                    bf16x8 bf = *(const bf16x8*)(s_w + (16 * ct + li) * 514 + lg * 8 + ko);
                    acc = MFMA16(af, bf, acc);
                }
                int base = kh * 1152 + (16 * ct + li) * 18 + 4 * lg;
                *(f32x2*)(s_gate + base) = (f32x2){acc[0], acc[1]};
                *(f32x2*)(s_gate + base + 2) = (f32x2){acc[2], acc[3]};
            }
            __syncthreads();
            if (tid < 256) {
                float gt[4];
#pragma unroll
                for (int g = 0; g < 4; ++g) {
                    int base = (g * 16 + cj) * 18 + cb;
                    gt[g] = s_gate[base] + s_gate[1152 + base] + bias[g];
                }
                c_reg = sigf(gt[1]) * c_reg + sigf(gt[0]) * tanhf_(gt[2]);
                float h = sigf(gt[3]) * tanhf_(c_reg);
                unsigned hu = f2bf(h);
                unsigned other = __shfl_xor(hu, 1);
                if ((cj & 1) == 0) {
                    unsigned long long v2 = (unsigned long long)(hu | (other << 16))
                                          | ((unsigned long long)(t + 1) << 32);
                    st_u64(h1w + (size_t)t * 2048 + cb * 128 + ((j0 + cj) >> 1), v2);
                }
            }
        }

        if (bi == 0) {
            float* s_red = s_gate;
            if (tid < 256) {
                int b = tid >> 4, kc = tid & 15;
                const unsigned long long* hw = h1w + (size_t)31 * 2048 + b * 128 + kc * 8;
                unsigned long long v[8];
                for (;;) {
#pragma unroll
                    for (int q = 0; q < 8; ++q) v[q] = ld_u64(hw + q);
                    bool ok = true;
#pragma unroll
                    for (int q = 0; q < 8; ++q) ok &= ((unsigned)(v[q] >> 32) == 32u);
                    if (ok) break;
                    __builtin_amdgcn_s_sleep(1);
                }
                float s = 0.f;
#pragma unroll
                for (int q = 0; q < 8; ++q) {
                    unsigned u = (unsigned)v[q];
                    s += Wfc[kc * 16 + 2 * q] * bf2f((unsigned short)(u & 0xffff));
                    s += Wfc[kc * 16 + 2 * q + 1] * bf2f((unsigned short)(u >> 16));
                }
                s_red[tid] = s;
            }
            __syncthreads();
            if (tid < 16) {
                float s = bfc[0];
#pragma unroll
                for (int q = 0; q < 16; ++q) s += s_red[tid * 16 + q];
                out[tid] = sigf(s);
            }
        }
    }
}

extern "C" void kernel_launch(void* const* d_in, const int* in_sizes, int n_in,
                              void* d_out, int out_size, void* d_ws, size_t ws_size,
                              hipStream_t stream) {
    const int*   adj  = (const int*)  d_in[0];
    const float* x    = (const float*)d_in[1];
    const float* W1   = (const float*)d_in[2];
    const float* b1   = (const float*)d_in[3];
    const float* W2   = (const float*)d_in[4];
    const float* b2   = (const float*)d_in[5];
    const float* Wih0 = (const float*)d_in[6];
    const float* Whh0 = (const float*)d_in[7];
    const float* bih0 = (const float*)d_in[8];
    const float* bhh0 = (const float*)d_in[9];
    const float* Wih1 = (const float*)d_in[10];
    const float* Whh1 = (const float*)d_in[11];
    const float* bih1 = (const float*)d_in[12];
    const float* bhh1 = (const float*)d_in[13];
    const float* Wfc  = (const float*)d_in[14];
    const float* bfc  = (const float*)d_in[15];
    float* out = (float*)d_out;

    if (ws_size < 5308416) return;   // ~5.1 MB scratch

    char* ws = (char*)d_ws;
    unsigned long long* xgw = (unsigned long long*)(ws);             // 4,194,304 B
    unsigned long long* h0w = (unsigned long long*)(ws + 4194304);   //   524,288 B
    unsigned long long* h1w = (unsigned long long*)(ws + 4718592);   //   524,288 B
    unsigned short* w1t = (unsigned short*)(ws + 5242880);           //    32,768 B
    unsigned short* w2t = (unsigned short*)(ws + 5275648);           //    32,768 B

    hipMemsetAsync(ws, 0, 5242880, stream);   // zero xg + h epochs
    k_prep<<<64, 256, 0, stream>>>(W1, W2, w1t, w2t);
    k_fused<<<536, 512, 0, stream>>>(adj, x, w1t, w2t, b1, b2,
                                     Wih0, bih0, bhh0, Whh0, Wih1, Whh1,
                                     bih1, bhh1, Wfc, bfc,
                                     xgw, h0w, h1w, out);
}